// Round 9
// baseline (112.344 us; speedup 1.0000x reference)
//
#include <hip/hip_runtime.h>
#include <math.h>

#define LL 1024
#define DD 640
#define KK 32
#define MM 64
#define THRESH 0.2f
#define LOG2E 1.4426950408889634f

// ws layout (float units)
#define NPROJ_OFF  0                        // [1024][64] node_proj + b_edge (backbone base)
#define NPROJC_OFF (NPROJ_OFF + LL * MM)    // [1024][64] node_proj + b_edge + W0 (contact base)
#define WRT_OFF    (NPROJC_OFF + LL * MM)   // ushort[64][32]: bf16 W_edge[2+k][m], m-major
#define W1_OFF     (WRT_OFF + 1024)         // 64 f32
#define EA_OFF     (W1_OFF + MM)            // 32 f32 : -log2e/(2 sigma^2)
#define EB_OFF     (EA_OFF + KK)            // 32 f32 :  log2e*mu/sigma^2
#define EC_OFF     (EB_OFF + KK)            // 32 f32 : -log2e*mu^2/(2 sigma^2)
#define XYZ4_OFF   (EC_OFF + KK)            // [1024][4] padded coords

typedef float f32x4_t __attribute__((ext_vector_type(4)));
typedef short bf16x8_t __attribute__((ext_vector_type(8)));

union FragU { unsigned int u[4]; bf16x8_t v; };

#if __has_builtin(__builtin_amdgcn_sqrtf)
#define FSQRT __builtin_amdgcn_sqrtf
#else
#define FSQRT sqrtf
#endif

#if __has_builtin(__builtin_amdgcn_exp2f)
#define EXP2F __builtin_amdgcn_exp2f
#else
#define EXP2F(x) __expf((x) * 0.6931471805599453f)
#endif

__device__ __forceinline__ unsigned int pack_bf(float hi, float lo) {
    return __builtin_amdgcn_perm(__float_as_uint(hi), __float_as_uint(lo), 0x07060302u);
}

// node_proj = S(1024x640) @ W_node(640x64) via MFMA; block 64 = constants.
__global__ __launch_bounds__(256) void prep_gemm(
    const float* __restrict__ S, const float* __restrict__ xyz,
    const float* __restrict__ rbf_mu, const float* __restrict__ rbf_sigma,
    const float* __restrict__ W_edge, const float* __restrict__ b_edge,
    const float* __restrict__ W_node, float* __restrict__ ws)
{
    const int b = blockIdx.x;
    const int t = threadIdx.x;
    if (b < 64) {
        const int lane = t & 63;
        const int wave = t >> 6;
        const int id   = b * 4 + wave;
        const int r0   = (id >> 2) * 16;
        const int n0   = (id & 3) * 16;
        const int col  = lane & 15;
        const int quad = lane >> 4;

        f32x4_t acc = {0.f, 0.f, 0.f, 0.f};
        const float* arow = S + (size_t)(r0 + col) * DD + quad * 8;
        const float* bcol = W_node + (size_t)(quad * 8) * MM + n0 + col;

        #pragma unroll 2
        for (int ks = 0; ks < 20; ++ks) {
            const float4 a0 = *(const float4*)(arow + ks * 32);
            const float4 a1 = *(const float4*)(arow + ks * 32 + 4);
            FragU A;
            A.u[0] = pack_bf(a0.y, a0.x); A.u[1] = pack_bf(a0.w, a0.z);
            A.u[2] = pack_bf(a1.y, a1.x); A.u[3] = pack_bf(a1.w, a1.z);
            const float* bk = bcol + (size_t)ks * 32 * MM;
            const float b0 = bk[0 * MM], b1 = bk[1 * MM], b2 = bk[2 * MM], b3 = bk[3 * MM];
            const float b4 = bk[4 * MM], b5 = bk[5 * MM], b6 = bk[6 * MM], b7 = bk[7 * MM];
            FragU B;
            B.u[0] = pack_bf(b1, b0); B.u[1] = pack_bf(b3, b2);
            B.u[2] = pack_bf(b5, b4); B.u[3] = pack_bf(b7, b6);
            acc = __builtin_amdgcn_mfma_f32_16x16x32_bf16(A.v, B.v, acc, 0, 0, 0);
        }
        const float bias = b_edge[n0 + col];
        const float w0   = W_edge[n0 + col];
        #pragma unroll
        for (int r = 0; r < 4; ++r) {
            const int row = r0 + quad * 4 + r;
            const float v = acc[r] + bias;
            ws[NPROJ_OFF  + (size_t)row * MM + n0 + col] = v;
            ws[NPROJC_OFF + (size_t)row * MM + n0 + col] = v + w0;
        }
    } else {
        unsigned short* wrt = (unsigned short*)(ws + WRT_OFF);
        if (t < MM) ws[W1_OFF + t] = W_edge[MM + t];
        if (t < KK) {
            const float s  = rbf_sigma[t];
            const float m_ = rbf_mu[t];
            const float inv = 1.0f / (2.0f * s * s);
            ws[EA_OFF + t] = -LOG2E * inv;
            ws[EB_OFF + t] =  2.0f * LOG2E * inv * m_;
            ws[EC_OFF + t] = -LOG2E * inv * m_ * m_;
        }
        for (int idx = t; idx < KK * MM; idx += 256) {
            const int m = idx >> 5, k = idx & 31;
            unsigned int u = __float_as_uint(W_edge[(2 + k) * MM + m]);
            u = (u + 0x7fffu + ((u >> 16) & 1u)) >> 16;   // RNE to bf16
            wrt[idx] = (unsigned short)u;
        }
        for (int n = t; n < LL; n += 256) {
            float4 v;
            v.x = xyz[3 * n + 0]; v.y = xyz[3 * n + 1];
            v.z = xyz[3 * n + 2]; v.w = 0.0f;
            *(float4*)(ws + XYZ4_OFF + 4 * n) = v;
        }
    }
}

// 512 blocks x 512 threads: block b owns rows {b, 1023-b} (exactly 1023 edges
// -> perfect balance); 8 waves stride 512 within each row. 2 blocks/CU
// resident = 16 waves/CU sustained.
__global__ __launch_bounds__(512, 4) void edge_kernel4(
    const float* __restrict__ P, const float* __restrict__ w_out,
    const float* __restrict__ ws, float* __restrict__ out)
{
    const int tid  = threadIdx.x;
    const int lane = tid & 63;
    const int wave = tid >> 6;
    const int quad = lane >> 4;
    const int col  = lane & 15;
    __shared__ float sred[8][3];

    const float* __restrict__ nproj  = ws + NPROJ_OFF;
    const float* __restrict__ nprojc = ws + NPROJC_OFF;
    const float4* __restrict__ xyz4  = (const float4*)(ws + XYZ4_OFF);
    const unsigned short* __restrict__ wrt = (const unsigned short*)(ws + WRT_OFF);

    // persistent frags
    FragU ar[4];
    float w1r[16], wvr[16];
    float aj[8], bj[8], cj[8];
    #pragma unroll
    for (int mt = 0; mt < 4; ++mt) {
        const uint4 w = *(const uint4*)(wrt + (mt * 16 + col) * KK + quad * 8);
        ar[mt].u[0] = w.x; ar[mt].u[1] = w.y; ar[mt].u[2] = w.z; ar[mt].u[3] = w.w;
        const f32x4_t w1 = *(const f32x4_t*)(ws + W1_OFF + mt * 16 + quad * 4);
        const f32x4_t wo = *(const f32x4_t*)(w_out + mt * 16 + quad * 4);
        #pragma unroll
        for (int r = 0; r < 4; ++r) { w1r[mt * 4 + r] = w1[r]; wvr[mt * 4 + r] = wo[r]; }
    }
    #pragma unroll
    for (int j = 0; j < 8; ++j) {
        aj[j] = ws[EA_OFF + quad * 8 + j];
        bj[j] = ws[EB_OFF + quad * 8 + j];
        cj[j] = ws[EC_OFF + quad * 8 + j];
    }

    const int b = (int)blockIdx.x;
    int rows[2];
    rows[0] = b;
    rows[1] = (LL - 1) - b;

    for (int rr = 0; rr < 2; ++rr) {
        const int i = rows[rr];
        const float4 xo = xyz4[i];
        const float xi0 = xo.x, xi1 = xo.y, xi2 = xo.z;
        const int len = (LL - 1) - i;
        float ax = 0.f, ay = 0.f, az = 0.f;
        const float* __restrict__ prow = P + (size_t)i * LL;

        for (int base = wave * 64; base < len; base += 512) {
            // ---- stage 1: 4 column-edge loads + distances (independent) ----
            float pcv[4], dnv[4], q2v[4], dxv[4], dyv[4], dzv[4];
            const float* npr[4];
            float peff[4];
            #pragma unroll
            for (int ct = 0; ct < 4; ++ct) {
                const int jo_n = base + ct * 16 + col;
                int jc = i + 1 + jo_n;
                jc = (jc < LL) ? jc : (LL - 1);
                pcv[ct] = prow[jc];
                const float4 xn = xyz4[jc];
                dxv[ct] = xn.x - xi0; dyv[ct] = xn.y - xi1; dzv[ct] = xn.z - xi2;
                q2v[ct] = fmaf(dxv[ct], dxv[ct],
                          fmaf(dyv[ct], dyv[ct],
                          fmaf(dzv[ct], dzv[ct], 1e-12f)));
                dnv[ct] = FSQRT(q2v[ct]);
                const bool bb = (jo_n == 0);
                peff[ct] = bb ? 1.0f : pcv[ct];
                npr[ct] = (bb ? nproj : nprojc) + (size_t)jc * MM;
            }

            // own edge via selects from stage-1 regs (own ct == quad)
            const int jo = base + lane;
            const bool valid = jo < len;
            float rx = dxv[0], ry = dyv[0], rz = dzv[0], p_own = pcv[0];
            rx = (quad == 1) ? dxv[1] : rx; rx = (quad == 2) ? dxv[2] : rx; rx = (quad == 3) ? dxv[3] : rx;
            ry = (quad == 1) ? dyv[1] : ry; ry = (quad == 2) ? dyv[2] : ry; ry = (quad == 3) ? dyv[3] : ry;
            rz = (quad == 1) ? dzv[1] : rz; rz = (quad == 2) ? dzv[2] : rz; rz = (quad == 3) ? dzv[3] : rz;
            p_own = (quad == 1) ? pcv[1] : p_own;
            p_own = (quad == 2) ? pcv[2] : p_own;
            p_own = (quad == 3) ? pcv[3] : p_own;
            const bool msk = valid && ((jo == 0) || ((jo >= 2) && (p_own > THRESH)));

            // ---- stage 2: 32 independent exps ----
            float e[4][8];
            #pragma unroll
            for (int ct = 0; ct < 4; ++ct)
                #pragma unroll
                for (int j = 0; j < 8; ++j)
                    e[ct][j] = EXP2F(fmaf(aj[j], q2v[ct], fmaf(bj[j], dnv[ct], cj[j])));

            // ---- stage 3: packs ----
            FragU bf[4];
            #pragma unroll
            for (int ct = 0; ct < 4; ++ct) {
                bf[ct].u[0] = pack_bf(e[ct][1], e[ct][0]);
                bf[ct].u[1] = pack_bf(e[ct][3], e[ct][2]);
                bf[ct].u[2] = pack_bf(e[ct][5], e[ct][4]);
                bf[ct].u[3] = pack_bf(e[ct][7], e[ct][6]);
            }

            // ---- stage 4: per-mt batched C-loads / rank-2 / MFMA / epilogue ----
            float g[4] = {0.f, 0.f, 0.f, 0.f};
            #pragma unroll
            for (int mt = 0; mt < 4; ++mt) {
                f32x4_t c[4];
                #pragma unroll
                for (int ct = 0; ct < 4; ++ct)
                    c[ct] = *(const f32x4_t*)(npr[ct] + mt * 16 + quad * 4);
                #pragma unroll
                for (int ct = 0; ct < 4; ++ct) {
                    c[ct][0] = fmaf(peff[ct], w1r[mt*4+0], c[ct][0]);
                    c[ct][1] = fmaf(peff[ct], w1r[mt*4+1], c[ct][1]);
                    c[ct][2] = fmaf(peff[ct], w1r[mt*4+2], c[ct][2]);
                    c[ct][3] = fmaf(peff[ct], w1r[mt*4+3], c[ct][3]);
                }
                #pragma unroll
                for (int ct = 0; ct < 4; ++ct)
                    c[ct] = __builtin_amdgcn_mfma_f32_16x16x32_bf16(ar[mt].v, bf[ct].v, c[ct], 0, 0, 0);
                #pragma unroll
                for (int ct = 0; ct < 4; ++ct) {
                    g[ct] = fmaf(fmaxf(c[ct][0], 0.f), wvr[mt*4+0], g[ct]);
                    g[ct] = fmaf(fmaxf(c[ct][1], 0.f), wvr[mt*4+1], g[ct]);
                    g[ct] = fmaf(fmaxf(c[ct][2], 0.f), wvr[mt*4+2], g[ct]);
                    g[ct] = fmaf(fmaxf(c[ct][3], 0.f), wvr[mt*4+3], g[ct]);
                }
            }

            // ---- stage 5: quad-partial reductions ----
            #pragma unroll
            for (int ct = 0; ct < 4; ++ct) g[ct] += __shfl_xor(g[ct], 16, 64);
            #pragma unroll
            for (int ct = 0; ct < 4; ++ct) g[ct] += __shfl_xor(g[ct], 32, 64);

            float gd = g[0];
            gd = (quad == 1) ? g[1] : gd;
            gd = (quad == 2) ? g[2] : gd;
            gd = (quad == 3) ? g[3] : gd;
            const float gate = msk ? (1.0f / (1.0f + __expf(-gd))) : 0.0f;
            ax = fmaf(gate, rx, ax);
            ay = fmaf(gate, ry, ay);
            az = fmaf(gate, rz, az);
        }

        // reduce 64 lanes, then 8 waves
        #pragma unroll
        for (int off = 32; off > 0; off >>= 1) {
            ax += __shfl_down(ax, off, 64);
            ay += __shfl_down(ay, off, 64);
            az += __shfl_down(az, off, 64);
        }
        if (lane == 0) { sred[wave][0] = ax; sred[wave][1] = ay; sred[wave][2] = az; }
        __syncthreads();
        if (tid == 0) {
            float tx = 0.f, ty = 0.f, tz = 0.f;
            #pragma unroll
            for (int w = 0; w < 8; ++w) {
                tx += sred[w][0]; ty += sred[w][1]; tz += sred[w][2];
            }
            out[i * 3 + 0] = xi0 + tx;
            out[i * 3 + 1] = xi1 + ty;
            out[i * 3 + 2] = xi2 + tz;
        }
        __syncthreads();   // protect sred before next row
    }
}

extern "C" void kernel_launch(void* const* d_in, const int* in_sizes, int n_in,
                              void* d_out, int out_size, void* d_ws, size_t ws_size,
                              hipStream_t stream) {
    const float* S         = (const float*)d_in[0];
    const float* P         = (const float*)d_in[1];
    const float* xyz       = (const float*)d_in[2];
    const float* rbf_mu    = (const float*)d_in[3];
    const float* rbf_sigma = (const float*)d_in[4];
    const float* W_edge    = (const float*)d_in[5];
    const float* b_edge    = (const float*)d_in[6];
    const float* W_node    = (const float*)d_in[7];
    const float* w_out     = (const float*)d_in[8];
    float* out = (float*)d_out;
    float* ws  = (float*)d_ws;

    prep_gemm<<<65, 256, 0, stream>>>(S, xyz, rbf_mu, rbf_sigma,
                                      W_edge, b_edge, W_node, ws);
    edge_kernel4<<<LL / 2, 512, 0, stream>>>(P, w_out, ws, out);
}

// Round 10
// 97.498 us; speedup vs baseline: 1.1523x; 1.1523x over previous
//
#include <hip/hip_runtime.h>
#include <math.h>

#define LL 1024
#define DD 640
#define KK 32
#define MM 64
#define THRESH 0.2f
#define LOG2E 1.4426950408889634f

// ws layout (float units)
#define NPROJ_OFF  0                        // [1024][64] node_proj + b_edge (backbone base)
#define NPROJC_OFF (NPROJ_OFF + LL * MM)    // [1024][64] node_proj + b_edge + W0 (contact base)
#define WRT_OFF    (NPROJC_OFF + LL * MM)   // ushort[64][32]: bf16 W_edge[2+k][m], m-major
#define W1_OFF     (WRT_OFF + 1024)         // 64 f32
#define EA_OFF     (W1_OFF + MM)            // 32 f32 : -log2e/(2 sigma^2)
#define EB_OFF     (EA_OFF + KK)            // 32 f32 :  log2e*mu/sigma^2
#define EC_OFF     (EB_OFF + KK)            // 32 f32 : -log2e*mu^2/(2 sigma^2)
#define XYZ4_OFF   (EC_OFF + KK)            // [1024][4] padded coords

typedef float f32x4_t __attribute__((ext_vector_type(4)));
typedef short bf16x8_t __attribute__((ext_vector_type(8)));

union FragU { unsigned int u[4]; bf16x8_t v; };

#if __has_builtin(__builtin_amdgcn_sqrtf)
#define FSQRT __builtin_amdgcn_sqrtf
#else
#define FSQRT sqrtf
#endif

#if __has_builtin(__builtin_amdgcn_exp2f)
#define EXP2F __builtin_amdgcn_exp2f
#else
#define EXP2F(x) __expf((x) * 0.6931471805599453f)
#endif

__device__ __forceinline__ unsigned int pack_bf(float hi, float lo) {
    return __builtin_amdgcn_perm(__float_as_uint(hi), __float_as_uint(lo), 0x07060302u);
}

// Split-K node_proj GEMM: 256 blocks, one 16x16 tile each; 4 waves split K=640
// into 160-chunks (5 MFMA steps), LDS-reduced. Block 256 = constants.
__global__ __launch_bounds__(256) void prep_sk(
    const float* __restrict__ S, const float* __restrict__ xyz,
    const float* __restrict__ rbf_mu, const float* __restrict__ rbf_sigma,
    const float* __restrict__ W_edge, const float* __restrict__ b_edge,
    const float* __restrict__ W_node, float* __restrict__ ws)
{
    const int b = blockIdx.x;
    const int t = threadIdx.x;
    if (b < 256) {
        __shared__ float red[4][64][4];
        const int lane = t & 63;
        const int wave = t >> 6;
        const int r0   = (b >> 2) * 16;     // row tile
        const int n0   = (b & 3) * 16;      // col tile
        const int col  = lane & 15;
        const int quad = lane >> 4;

        f32x4_t acc = {0.f, 0.f, 0.f, 0.f};
        const float* arow = S + (size_t)(r0 + col) * DD + wave * 160 + quad * 8;
        const float* bcol = W_node + (size_t)(wave * 160 + quad * 8) * MM + n0 + col;

        #pragma unroll
        for (int ks = 0; ks < 5; ++ks) {
            const float4 a0 = *(const float4*)(arow + ks * 32);
            const float4 a1 = *(const float4*)(arow + ks * 32 + 4);
            FragU A;
            A.u[0] = pack_bf(a0.y, a0.x); A.u[1] = pack_bf(a0.w, a0.z);
            A.u[2] = pack_bf(a1.y, a1.x); A.u[3] = pack_bf(a1.w, a1.z);
            const float* bk = bcol + (size_t)ks * 32 * MM;
            const float b0 = bk[0 * MM], b1 = bk[1 * MM], b2 = bk[2 * MM], b3 = bk[3 * MM];
            const float b4 = bk[4 * MM], b5 = bk[5 * MM], b6 = bk[6 * MM], b7 = bk[7 * MM];
            FragU B;
            B.u[0] = pack_bf(b1, b0); B.u[1] = pack_bf(b3, b2);
            B.u[2] = pack_bf(b5, b4); B.u[3] = pack_bf(b7, b6);
            acc = __builtin_amdgcn_mfma_f32_16x16x32_bf16(A.v, B.v, acc, 0, 0, 0);
        }
        red[wave][lane][0] = acc[0];
        red[wave][lane][1] = acc[1];
        red[wave][lane][2] = acc[2];
        red[wave][lane][3] = acc[3];
        __syncthreads();
        // reduce: thread t -> (lane lr, reg) pair; C/D map row=r0+(lr>>4)*4+reg
        const int lr  = t & 63;
        const int reg = t >> 6;
        const float v = (red[0][lr][reg] + red[1][lr][reg])
                      + (red[2][lr][reg] + red[3][lr][reg]);
        const int row = r0 + (lr >> 4) * 4 + reg;
        const int cc  = n0 + (lr & 15);
        const float vb = v + b_edge[cc];
        ws[NPROJ_OFF  + (size_t)row * MM + cc] = vb;
        ws[NPROJC_OFF + (size_t)row * MM + cc] = vb + W_edge[cc];
    } else {
        // constants + padded xyz
        unsigned short* wrt = (unsigned short*)(ws + WRT_OFF);
        if (t < MM) ws[W1_OFF + t] = W_edge[MM + t];
        if (t < KK) {
            const float s  = rbf_sigma[t];
            const float m_ = rbf_mu[t];
            const float inv = 1.0f / (2.0f * s * s);
            ws[EA_OFF + t] = -LOG2E * inv;
            ws[EB_OFF + t] =  2.0f * LOG2E * inv * m_;
            ws[EC_OFF + t] = -LOG2E * inv * m_ * m_;
        }
        for (int idx = t; idx < KK * MM; idx += 256) {
            const int m = idx >> 5, k = idx & 31;
            unsigned int u = __float_as_uint(W_edge[(2 + k) * MM + m]);
            u = (u + 0x7fffu + ((u >> 16) & 1u)) >> 16;   // RNE to bf16
            wrt[idx] = (unsigned short)u;
        }
        for (int n = t; n < LL; n += 256) {
            float4 v;
            v.x = xyz[3 * n + 0]; v.y = xyz[3 * n + 1];
            v.z = xyz[3 * n + 2]; v.w = 0.0f;
            *(float4*)(ws + XYZ4_OFF + 4 * n) = v;
        }
    }
}

// Stage-parallel edge kernel (round-8 best: 99.4 us config), unchanged.
__global__ __launch_bounds__(256) void edge_kernel3(
    const float* __restrict__ P, const float* __restrict__ w_out,
    const float* __restrict__ ws, float* __restrict__ out)
{
    const int tid  = threadIdx.x;
    const int lane = tid & 63;
    const int wave = tid >> 6;
    const int quad = lane >> 4;
    const int col  = lane & 15;
    __shared__ float sred[4][3];

    const float* __restrict__ nproj  = ws + NPROJ_OFF;
    const float* __restrict__ nprojc = ws + NPROJC_OFF;
    const float4* __restrict__ xyz4  = (const float4*)(ws + XYZ4_OFF);
    const unsigned short* __restrict__ wrt = (const unsigned short*)(ws + WRT_OFF);

    FragU ar[4];
    float w1r[16], wvr[16];
    float aj[8], bj[8], cj[8];
    #pragma unroll
    for (int mt = 0; mt < 4; ++mt) {
        const uint4 w = *(const uint4*)(wrt + (mt * 16 + col) * KK + quad * 8);
        ar[mt].u[0] = w.x; ar[mt].u[1] = w.y; ar[mt].u[2] = w.z; ar[mt].u[3] = w.w;
        const f32x4_t w1 = *(const f32x4_t*)(ws + W1_OFF + mt * 16 + quad * 4);
        const f32x4_t wo = *(const f32x4_t*)(w_out + mt * 16 + quad * 4);
        #pragma unroll
        for (int r = 0; r < 4; ++r) { w1r[mt * 4 + r] = w1[r]; wvr[mt * 4 + r] = wo[r]; }
    }
    #pragma unroll
    for (int j = 0; j < 8; ++j) {
        aj[j] = ws[EA_OFF + quad * 8 + j];
        bj[j] = ws[EB_OFF + quad * 8 + j];
        cj[j] = ws[EC_OFF + quad * 8 + j];
    }

    const int i = (int)blockIdx.x;
    const float4 xo = xyz4[i];
    const float xi0 = xo.x, xi1 = xo.y, xi2 = xo.z;
    const int len = (LL - 1) - i;
    float ax = 0.f, ay = 0.f, az = 0.f;
    const float* __restrict__ prow = P + (size_t)i * LL;

    for (int base = wave * 64; base < len; base += 256) {
        float pcv[4], dnv[4], q2v[4], dxv[4], dyv[4], dzv[4];
        const float* npr[4];
        float peff[4];
        #pragma unroll
        for (int ct = 0; ct < 4; ++ct) {
            const int jo_n = base + ct * 16 + col;
            int jc = i + 1 + jo_n;
            jc = (jc < LL) ? jc : (LL - 1);
            pcv[ct] = prow[jc];
            const float4 xn = xyz4[jc];
            dxv[ct] = xn.x - xi0; dyv[ct] = xn.y - xi1; dzv[ct] = xn.z - xi2;
            q2v[ct] = fmaf(dxv[ct], dxv[ct],
                      fmaf(dyv[ct], dyv[ct],
                      fmaf(dzv[ct], dzv[ct], 1e-12f)));
            dnv[ct] = FSQRT(q2v[ct]);
            const bool bb = (jo_n == 0);
            peff[ct] = bb ? 1.0f : pcv[ct];
            npr[ct] = (bb ? nproj : nprojc) + (size_t)jc * MM;
        }

        const int jo = base + lane;
        const bool valid = jo < len;
        float rx = dxv[0], ry = dyv[0], rz = dzv[0], p_own = pcv[0];
        rx = (quad == 1) ? dxv[1] : rx; rx = (quad == 2) ? dxv[2] : rx; rx = (quad == 3) ? dxv[3] : rx;
        ry = (quad == 1) ? dyv[1] : ry; ry = (quad == 2) ? dyv[2] : ry; ry = (quad == 3) ? dyv[3] : ry;
        rz = (quad == 1) ? dzv[1] : rz; rz = (quad == 2) ? dzv[2] : rz; rz = (quad == 3) ? dzv[3] : rz;
        p_own = (quad == 1) ? pcv[1] : p_own;
        p_own = (quad == 2) ? pcv[2] : p_own;
        p_own = (quad == 3) ? pcv[3] : p_own;
        const bool msk = valid && ((jo == 0) || ((jo >= 2) && (p_own > THRESH)));

        float e[4][8];
        #pragma unroll
        for (int ct = 0; ct < 4; ++ct)
            #pragma unroll
            for (int j = 0; j < 8; ++j)
                e[ct][j] = EXP2F(fmaf(aj[j], q2v[ct], fmaf(bj[j], dnv[ct], cj[j])));

        FragU bf[4];
        #pragma unroll
        for (int ct = 0; ct < 4; ++ct) {
            bf[ct].u[0] = pack_bf(e[ct][1], e[ct][0]);
            bf[ct].u[1] = pack_bf(e[ct][3], e[ct][2]);
            bf[ct].u[2] = pack_bf(e[ct][5], e[ct][4]);
            bf[ct].u[3] = pack_bf(e[ct][7], e[ct][6]);
        }

        float g[4] = {0.f, 0.f, 0.f, 0.f};
        #pragma unroll
        for (int mt = 0; mt < 4; ++mt) {
            f32x4_t c[4];
            #pragma unroll
            for (int ct = 0; ct < 4; ++ct)
                c[ct] = *(const f32x4_t*)(npr[ct] + mt * 16 + quad * 4);
            #pragma unroll
            for (int ct = 0; ct < 4; ++ct) {
                c[ct][0] = fmaf(peff[ct], w1r[mt*4+0], c[ct][0]);
                c[ct][1] = fmaf(peff[ct], w1r[mt*4+1], c[ct][1]);
                c[ct][2] = fmaf(peff[ct], w1r[mt*4+2], c[ct][2]);
                c[ct][3] = fmaf(peff[ct], w1r[mt*4+3], c[ct][3]);
            }
            #pragma unroll
            for (int ct = 0; ct < 4; ++ct)
                c[ct] = __builtin_amdgcn_mfma_f32_16x16x32_bf16(ar[mt].v, bf[ct].v, c[ct], 0, 0, 0);
            #pragma unroll
            for (int ct = 0; ct < 4; ++ct) {
                g[ct] = fmaf(fmaxf(c[ct][0], 0.f), wvr[mt*4+0], g[ct]);
                g[ct] = fmaf(fmaxf(c[ct][1], 0.f), wvr[mt*4+1], g[ct]);
                g[ct] = fmaf(fmaxf(c[ct][2], 0.f), wvr[mt*4+2], g[ct]);
                g[ct] = fmaf(fmaxf(c[ct][3], 0.f), wvr[mt*4+3], g[ct]);
            }
        }

        #pragma unroll
        for (int ct = 0; ct < 4; ++ct) g[ct] += __shfl_xor(g[ct], 16, 64);
        #pragma unroll
        for (int ct = 0; ct < 4; ++ct) g[ct] += __shfl_xor(g[ct], 32, 64);

        float gd = g[0];
        gd = (quad == 1) ? g[1] : gd;
        gd = (quad == 2) ? g[2] : gd;
        gd = (quad == 3) ? g[3] : gd;
        const float gate = msk ? (1.0f / (1.0f + __expf(-gd))) : 0.0f;
        ax = fmaf(gate, rx, ax);
        ay = fmaf(gate, ry, ay);
        az = fmaf(gate, rz, az);
    }

    #pragma unroll
    for (int off = 32; off > 0; off >>= 1) {
        ax += __shfl_down(ax, off, 64);
        ay += __shfl_down(ay, off, 64);
        az += __shfl_down(az, off, 64);
    }
    if (lane == 0) { sred[wave][0] = ax; sred[wave][1] = ay; sred[wave][2] = az; }
    __syncthreads();
    if (tid == 0) {
        const float tx = (sred[0][0] + sred[1][0]) + (sred[2][0] + sred[3][0]);
        const float ty = (sred[0][1] + sred[1][1]) + (sred[2][1] + sred[3][1]);
        const float tz = (sred[0][2] + sred[1][2]) + (sred[2][2] + sred[3][2]);
        out[i * 3 + 0] = xi0 + tx;
        out[i * 3 + 1] = xi1 + ty;
        out[i * 3 + 2] = xi2 + tz;
    }
}

extern "C" void kernel_launch(void* const* d_in, const int* in_sizes, int n_in,
                              void* d_out, int out_size, void* d_ws, size_t ws_size,
                              hipStream_t stream) {
    const float* S         = (const float*)d_in[0];
    const float* P         = (const float*)d_in[1];
    const float* xyz       = (const float*)d_in[2];
    const float* rbf_mu    = (const float*)d_in[3];
    const float* rbf_sigma = (const float*)d_in[4];
    const float* W_edge    = (const float*)d_in[5];
    const float* b_edge    = (const float*)d_in[6];
    const float* W_node    = (const float*)d_in[7];
    const float* w_out     = (const float*)d_in[8];
    float* out = (float*)d_out;
    float* ws  = (float*)d_ws;

    prep_sk<<<257, 256, 0, stream>>>(S, xyz, rbf_mu, rbf_sigma,
                                     W_edge, b_edge, W_node, ws);
    edge_kernel3<<<LL, 256, 0, stream>>>(P, w_out, ws, out);
}